// Round 6
// baseline (536.048 us; speedup 1.0000x reference)
//
#include <hip/hip_runtime.h>

typedef unsigned short u16;
typedef short short8 __attribute__((ext_vector_type(8)));
typedef short short4v __attribute__((ext_vector_type(4)));
typedef float floatx4 __attribute__((ext_vector_type(4)));
typedef float floatx4v __attribute__((ext_vector_type(4)));

#define SQ 2048
#define NH 16
#define HD 128
#define RD 64
#define NB 2
#define LDKV 5120
#define LDQ 3072

// padded LDS strides (odd multiples of 8 u16 = 16 B)
#define LKC 136
#define LKR 72
#define LVT 72
#define LP  72

__device__ __forceinline__ float bf2f(u16 u) {
  union { unsigned u; float f; } v; v.u = ((unsigned)u) << 16; return v.f;
}
__device__ __forceinline__ u16 f2bf(float f) {
  union { float f; unsigned u; } v; v.f = f;
  return (u16)((v.u + 0x7FFFu + ((v.u >> 16) & 1u)) >> 16);
}
__device__ __forceinline__ void gll16(const u16* g, u16* l) {
  __builtin_amdgcn_global_load_lds((const __attribute__((address_space(1))) void*)g,
                                   (__attribute__((address_space(3))) void*)l, 16, 0, 0);
}

// ---- x (f32) -> bf16, vectorized ----
__global__ __launch_bounds__(256) void convert_x(const float* __restrict__ src,
                                                 u16* __restrict__ dst, int n4) {
  const int i = blockIdx.x * 256 + threadIdx.x;
  if (i >= n4) return;
  const floatx4v v = *(const floatx4v*)(src + 4 * (size_t)i);
  short4v o;
  o.x = (short)f2bf(v.x); o.y = (short)f2bf(v.y);
  o.z = (short)f2bf(v.z); o.w = (short)f2bf(v.w);
  *(short4v*)(dst + 4 * (size_t)i) = o;
}

// ---- all 8 biases (f32) -> concatenated bf16 slots ----
__global__ __launch_bounds__(256) void convert_biases(
    const float* b0, const float* b1, const float* b2, const float* b3,
    const float* b4, const float* b5, const float* b6, const float* b7,
    u16* __restrict__ bc) {
  const int i = blockIdx.x * 256 + threadIdx.x;
  if (i >= 12288) return;
  float v;
  if      (i < 512)   v = b0[i];          // kvdb
  else if (i < 2048)  v = b1[i - 512];    // qdb
  else if (i < 4096)  v = b2[i - 2048];   // kub
  else if (i < 6144)  v = b3[i - 4096];   // vub
  else if (i < 7168)  v = b4[i - 6144];   // krb
  else if (i < 9216)  v = b5[i - 7168];   // qub
  else if (i < 10240) v = b6[i - 9216];   // qrb
  else                v = b7[i - 10240];  // ob
  bc[i] = f2bf(v);
}

// ---- weight transpose: in[R][C] f32 -> out[C][R] bf16 ----
__global__ __launch_bounds__(256) void transpose_w(const float* __restrict__ in,
                                                   u16* __restrict__ out,
                                                   int R, int C) {
  __shared__ u16 tile[32][33];
  const int c0 = blockIdx.x * 32, r0 = blockIdx.y * 32;
  const int x = threadIdx.x & 31, y = threadIdx.x >> 5;
#pragma unroll
  for (int i = 0; i < 32; i += 8)
    tile[y + i][x] = f2bf(in[(size_t)(r0 + y + i) * C + c0 + x]);
  __syncthreads();
#pragma unroll
  for (int i = 0; i < 32; i += 8)
    out[(size_t)(c0 + y + i) * R + r0 + x] = tile[x][y + i];
}

// ---- V (cols 2048..4095 of KV [4096,5120]) -> Vt [B,H,HD,S] ----
__global__ __launch_bounds__(256) void transpose_v(const u16* __restrict__ KV,
                                                   u16* __restrict__ Vt) {
  __shared__ u16 tile[32][33];
  const int bh = blockIdx.z, b = bh >> 4, hh = bh & 15;
  const u16* pin = KV + (size_t)b * SQ * LDKV + 2048 + (size_t)hh * HD;
  u16* pout = Vt + (size_t)bh * HD * SQ;
  const int s0 = blockIdx.x * 32, d0 = blockIdx.y * 32;
  const int x = threadIdx.x & 31, y = threadIdx.x >> 5;
#pragma unroll
  for (int i = 0; i < 32; i += 8)
    tile[y + i][x] = pin[(size_t)(s0 + y + i) * LDKV + d0 + x];
  __syncthreads();
#pragma unroll
  for (int i = 0; i < 32; i += 8)
    pout[(size_t)(d0 + y + i) * SQ + s0 + x] = tile[x][y + i];
}

// ---- RoPE in place on a [4096 x (16*64)] submatrix at col `coloff`, ld `ld` ----
__global__ __launch_bounds__(256) void rope_inplace(u16* __restrict__ buf,
                                                    int ld, int coloff) {
  const int i = blockIdx.x * 256 + threadIdx.x;
  if (i >= NB * SQ * NH * 32) return;
  const int j = i & 31;
  const int hh = (i >> 5) & 15;
  const int row = i >> 9;
  const int s = row & (SQ - 1);
  u16* p = buf + (size_t)row * ld + coloff + hh * RD + 2 * j;
  const float x1 = bf2f(p[0]), x2 = bf2f(p[1]);
  const float inv = exp2f(-(float)j * 0.41524101186092031f);  // 10000^(-j/32)
  const float ang = (float)s * inv;
  float sn, cs;
  sincosf(ang, &sn, &cs);
  p[0] = f2bf(x1 * cs - x2 * sn);
  p[1] = f2bf(x1 * sn + x2 * cs);
}

// ---- C[M=4096,N] = A[.,K](lda) * Bt[N,K]^T + bias; out bf16(ldc) or f32 ----
// r6: T3-minimal 2-phase double-buffer (guide §5.5 T3 recipe, verified m248v2):
// issue next tile's 4 global_load_lds BEFORE computing current buffer, single
// __syncthreads per K-step — its vmcnt(0) lands after ~300cy of MFMA+ds_read,
// so load latency is hidden by ILP (our grids give only 2 blocks/CU of TLP,
// which is why the old stage->drain->compute loop sat at ~390 TF; m102 shape
// curve). Buffers stay [128][32] conflict-free, linear gll16 dests (rule #21),
// MFMA order unchanged -> bit-identical epilogue. Rider: bijective XCD swizzle
// (T1; all grids %8==0) for A-panel L2 locality.
__global__ __launch_bounds__(256) void gemm_bt(const u16* __restrict__ A, int lda,
                                               const u16* __restrict__ Bt,
                                               const u16* __restrict__ bias,
                                               void* __restrict__ Cout, int ldc,
                                               int wf32, int N, int K) {
  __shared__ __align__(16) u16 lA[2][128 * 32];
  __shared__ __align__(16) u16 lB[2][128 * 32];
  const int t = threadIdx.x;
  const int lane = t & 63, w = t >> 6;
  const int wm = w & 1, wn = w >> 1;
  // XCD-aware block swizzle: hw block -> work id so same-XCD blocks are a
  // contiguous chunk (share A panels in that XCD's L2). nwg % 8 == 0 for all
  // our grids (512/1280/768), so this is bijective.
  const int gx = gridDim.x;
  const int nwg = gx * gridDim.y;
  const int bid = blockIdx.y * gx + blockIdx.x;
  const int cpx = nwg >> 3;
  const int sbid = (bid & 7) * cpx + (bid >> 3);
  const int m0 = (sbid / gx) * 128, n0 = (sbid % gx) * 128;
  const int srow = t >> 2, scol = (t & 3) * 8;
  const u16* gA = A + (size_t)(m0 + srow) * lda + scol;
  const u16* gB = Bt + (size_t)(n0 + srow) * K + scol;
  const int lane_m = lane & 15, lane_k = (lane >> 4) * 8;

  auto stage = [&](int b, int k0) {
    gll16(gA + k0, lA[b] + (16 * w) * 32);
    gll16(gA + (size_t)64 * lda + k0, lA[b] + (64 + 16 * w) * 32);
    gll16(gB + k0, lB[b] + (16 * w) * 32);
    gll16(gB + (size_t)64 * K + k0, lB[b] + (64 + 16 * w) * 32);
  };

  floatx4 acc[4][4] = {};
  stage(0, 0);
  __syncthreads();
  int cur = 0;
  for (int k0 = 0; k0 < K; k0 += 32) {
    if (k0 + 32 < K) stage(cur ^ 1, k0 + 32);  // loads fly during compute below
    short8 af[4], bf[4];
#pragma unroll
    for (int i = 0; i < 4; i++)
      af[i] = *(const short8*)(lA[cur] + (wm * 64 + i * 16 + lane_m) * 32 + lane_k);
#pragma unroll
    for (int i = 0; i < 4; i++)
      bf[i] = *(const short8*)(lB[cur] + (wn * 64 + i * 16 + lane_m) * 32 + lane_k);
#pragma unroll
    for (int mi = 0; mi < 4; mi++)
#pragma unroll
      for (int ni = 0; ni < 4; ni++)
        acc[mi][ni] = __builtin_amdgcn_mfma_f32_16x16x32_bf16(af[mi], bf[ni], acc[mi][ni], 0, 0, 0);
    __syncthreads();  // vmcnt(0)+lgkmcnt(0)+barrier: next buffer ready, cur free
    cur ^= 1;
  }
  const int quad = lane >> 4;
#pragma unroll
  for (int ni = 0; ni < 4; ni++) {
    const int col = n0 + wn * 64 + ni * 16 + lane_m;
    const float bv = bf2f(bias[col]);
#pragma unroll
    for (int mi = 0; mi < 4; mi++) {
      const int row = m0 + wm * 64 + mi * 16 + quad * 4;
      if (wf32) {
        float* pc = (float*)Cout + (size_t)row * ldc + col;
#pragma unroll
        for (int r = 0; r < 4; r++)
          pc[(size_t)r * ldc] = acc[mi][ni][r] + bv;
      } else {
        u16* pc = (u16*)Cout + (size_t)row * ldc + col;
#pragma unroll
        for (int r = 0; r < 4; r++)
          pc[(size_t)r * ldc] = f2bf(acc[mi][ni][r] + bv);
      }
    }
  }
}

// ---- flash attention: grid (16, 32); 8 waves, 128 q-rows/block, 64-key tiles ----
// r5 verified at 158 us (structure + setprio). r6 adds T13 defer-max: skip the
// O-rescale (128 scalar mults, ~20% of softmax VALU) when no row's tile max
// grew past mrow+28.8 (raw units; bound P <= 2^3 = 8 — safe in f32 accum and
// bf16 P, normalization cancels scale). Wave-uniform __any branch.
__global__ __launch_bounds__(512, 4) void flash_attn(const u16* __restrict__ Q,
                                                     const u16* __restrict__ KV,
                                                     const u16* __restrict__ Vt,
                                                     u16* __restrict__ Ctx) {
  __shared__ __align__(16) u16 lKc[64 * LKC];
  __shared__ __align__(16) u16 lKr[64 * LKR];
  __shared__ __align__(16) u16 lVt[128 * LVT];
  __shared__ __align__(16) u16 lP[8 * 16 * LP];
  const int t = threadIdx.x, lane = t & 63, w = t >> 6;
  const int col = blockIdx.y;
  const int qtile = (col < 16) ? (15 - (int)blockIdx.x) : (int)blockIdx.x;
  const int h = col & (NH - 1);
  const int b = col >> 4;
  const int q0 = qtile * 128;
  const int nkt = 2 * qtile + 2;
  const int lane_m = lane & 15, quad = lane >> 4, lane_k = quad * 8;

  // Q fragments (A-operand), one 16-row stripe per wave
  const int qrow = q0 + 16 * w + lane_m;
  const u16* qcp = Q + (size_t)(b * SQ + qrow) * LDQ + h * HD;
  const u16* qrp = Q + (size_t)(b * SQ + qrow) * LDQ + 2048 + h * RD;
  short8 qfc[4], qfr[2];
#pragma unroll
  for (int ks = 0; ks < 4; ks++) qfc[ks] = *(const short8*)(qcp + ks * 32 + lane_k);
#pragma unroll
  for (int ks = 0; ks < 2; ks++) qfr[ks] = *(const short8*)(qrp + ks * 32 + lane_k);

  floatx4 O[8] = {};
  float mrow[4], lsum[4];
#pragma unroll
  for (int r = 0; r < 4; r++) { mrow[r] = -1e30f; lsum[r] = 0.f; }

  const u16* gKc = KV + (size_t)b * SQ * LDKV + h * HD;          // + key*LDKV + d
  const u16* gKr = KV + (size_t)b * SQ * LDKV + 4096 + h * RD;   // + key*LDKV + d
  const u16* gVt = Vt + (size_t)(b * NH + h) * HD * SQ;          // + d*SQ + key
  const float C2 = 0.10412825525540364f;  // (1/sqrt(192)) * log2(e)
  const float THR = 28.8f;                // defer-max threshold: exp2(THR*C2)=8

  // register staging (global -> reg prefetch -> LDS), 512 threads
  short8 rKc[2], rKr, rVt[2];
  auto load_tile = [&](int kb) {
#pragma unroll
    for (int i = 0; i < 2; i++) {
      const int c = t + i * 512, row = c >> 4, cc = (c & 15) * 8;
      rKc[i] = *(const short8*)(gKc + (size_t)(kb + row) * LDKV + cc);
    }
    {
      const int row = t >> 3, cc = (t & 7) * 8;
      rKr = *(const short8*)(gKr + (size_t)(kb + row) * LDKV + cc);
    }
#pragma unroll
    for (int i = 0; i < 2; i++) {
      const int c = t + i * 512, row = c >> 3, cc = (c & 7) * 8;
      rVt[i] = *(const short8*)(gVt + (size_t)row * SQ + kb + cc);
    }
  };

  const int wrow_lo = q0 + 16 * w;
  const int wrow_hi = wrow_lo + 15;

  load_tile(0);
  for (int kt = 0; kt < nkt; kt++) {
    const int kb = kt * 64;
    __syncthreads();  // previous tile's LDS reads complete
#pragma unroll
    for (int i = 0; i < 2; i++) {
      const int c = t + i * 512, row = c >> 4, cc = (c & 15) * 8;
      *(short8*)(lKc + row * LKC + cc) = rKc[i];
    }
    {
      const int row = t >> 3, cc = (t & 7) * 8;
      *(short8*)(lKr + row * LKR + cc) = rKr;
    }
#pragma unroll
    for (int i = 0; i < 2; i++) {
      const int c = t + i * 512, row = c >> 3, cc = (c & 7) * 8;
      *(short8*)(lVt + row * LVT + cc) = rVt[i];
    }
    __syncthreads();
    if (kt < nkt - 1) load_tile(kb + 64);  // prefetch overlaps compute below

    if (kb <= wrow_hi) {  // wave-level skip of fully-masked tiles (barriers stay uniform)
      float ss[4][4];
      __builtin_amdgcn_s_setprio(1);
#pragma unroll
      for (int n = 0; n < 4; n++) {
        floatx4 a = {0.f, 0.f, 0.f, 0.f};
#pragma unroll
        for (int ks = 0; ks < 4; ks++) {
          const short8 kf = *(const short8*)(lKc + (n * 16 + lane_m) * LKC + ks * 32 + lane_k);
          a = __builtin_amdgcn_mfma_f32_16x16x32_bf16(qfc[ks], kf, a, 0, 0, 0);
        }
#pragma unroll
        for (int ks = 0; ks < 2; ks++) {
          const short8 kf = *(const short8*)(lKr + (n * 16 + lane_m) * LKR + ks * 32 + lane_k);
          a = __builtin_amdgcn_mfma_f32_16x16x32_bf16(qfr[ks], kf, a, 0, 0, 0);
        }
#pragma unroll
        for (int r = 0; r < 4; r++) ss[n][r] = a[r];
      }
      __builtin_amdgcn_s_setprio(0);
      if (kb + 63 > wrow_lo) {  // causal mask (partial tiles)
#pragma unroll
        for (int n = 0; n < 4; n++) {
          const int kcol = kb + n * 16 + lane_m;
#pragma unroll
          for (int r = 0; r < 4; r++) {
            const int row = wrow_lo + quad * 4 + r;
            if (kcol > row) ss[n][r] = -1e30f;
          }
        }
      }
      // per-row tile max
      float mt[4];
#pragma unroll
      for (int r = 0; r < 4; r++) {
        float m = fmaxf(fmaxf(ss[0][r], ss[1][r]), fmaxf(ss[2][r], ss[3][r]));
#pragma unroll
        for (int d = 1; d < 16; d <<= 1) m = fmaxf(m, __shfl_xor(m, d));
        mt[r] = m;
      }
      // T13 defer-max: rescale only if some row grew past THR
      const bool grow = (mt[0] > mrow[0] + THR) || (mt[1] > mrow[1] + THR) ||
                        (mt[2] > mrow[2] + THR) || (mt[3] > mrow[3] + THR);
      if (__any(grow)) {
#pragma unroll
        for (int r = 0; r < 4; r++) {
          const float mn = fmaxf(mrow[r], mt[r]);
          const float alpha = exp2f((mrow[r] - mn) * C2);
          mrow[r] = mn;
          lsum[r] *= alpha;
#pragma unroll
          for (int vb = 0; vb < 8; vb++) O[vb][r] *= alpha;
        }
      }
      float pw[4][4];
#pragma unroll
      for (int r = 0; r < 4; r++) {
        float s = 0.f;
#pragma unroll
        for (int n = 0; n < 4; n++) {
          const float p = exp2f((ss[n][r] - mrow[r]) * C2);
          pw[n][r] = p;
          s += p;
        }
#pragma unroll
        for (int d = 1; d < 16; d <<= 1) s += __shfl_xor(s, d);
        lsum[r] += s;
      }
      // P: C-layout -> LDS (per-wave region) -> A-layout
#pragma unroll
      for (int n = 0; n < 4; n++)
#pragma unroll
        for (int r = 0; r < 4; r++)
          lP[(w * 16 + quad * 4 + r) * LP + n * 16 + lane_m] = f2bf(pw[n][r]);
      asm volatile("s_waitcnt lgkmcnt(0)" ::: "memory");
      __builtin_amdgcn_s_setprio(1);
#pragma unroll
      for (int ks = 0; ks < 2; ks++) {
        const short8 pf = *(const short8*)(lP + (w * 16 + lane_m) * LP + ks * 32 + lane_k);
#pragma unroll
        for (int vb = 0; vb < 8; vb++) {
          const short8 vf = *(const short8*)(lVt + (vb * 16 + lane_m) * LVT + ks * 32 + lane_k);
          O[vb] = __builtin_amdgcn_mfma_f32_16x16x32_bf16(pf, vf, O[vb], 0, 0, 0);
        }
      }
      __builtin_amdgcn_s_setprio(0);
    }
  }
  float inv[4];
#pragma unroll
  for (int r = 0; r < 4; r++) inv[r] = 1.f / lsum[r];
#pragma unroll
  for (int vb = 0; vb < 8; vb++) {
#pragma unroll
    for (int r = 0; r < 4; r++) {
      const int row = wrow_lo + quad * 4 + r;
      Ctx[(size_t)(b * SQ + row) * 2048 + h * HD + vb * 16 + lane_m] = f2bf(O[vb][r] * inv[r]);
    }
  }
}

extern "C" void kernel_launch(void* const* d_in, const int* in_sizes, int n_in,
                              void* d_out, int out_size, void* d_ws, size_t ws_size,
                              hipStream_t stream) {
  (void)in_sizes; (void)n_in; (void)out_size; (void)ws_size;
  const float* x    = (const float*)d_in[0];
  const float* kvdw = (const float*)d_in[2];
  const float* kvdb = (const float*)d_in[3];
  const float* kuw  = (const float*)d_in[4];
  const float* kub  = (const float*)d_in[5];
  const float* vuw  = (const float*)d_in[6];
  const float* vub  = (const float*)d_in[7];
  const float* krw  = (const float*)d_in[8];
  const float* krb  = (const float*)d_in[9];
  const float* qdw  = (const float*)d_in[10];
  const float* qdb  = (const float*)d_in[11];
  const float* quw  = (const float*)d_in[12];
  const float* qub  = (const float*)d_in[13];
  const float* qrw  = (const float*)d_in[14];
  const float* qrb  = (const float*)d_in[15];
  const float* ow   = (const float*)d_in[16];
  const float* ob   = (const float*)d_in[17];

  // workspace layout (u16 units), ~115 MB, lifetime-aliased
  u16* p = (u16*)d_ws;
  u16* bc   = p;  p += 16384;
  u16* WT1  = p;  p += (size_t)2048 * 2048;  // kvd^T | qd^T   [2048,2048]
  u16* WT2  = p;  p += (size_t)5120 * 512;   // ku^T|vu^T|kr^T [5120,512]
  u16* WT3  = p;  p += (size_t)3072 * 1536;  // qu^T|qr^T      [3072,1536]
  u16* Ctx  = WT1;                           // overlays WT1..WT3 (dead by flash)
  u16* WTo  = p;  p += (size_t)2048 * 2048;  // o^T            [2048,2048]
  u16* KVQd = p;  p += (size_t)4096 * 2048;  // kv_c|q_c       [4096,2048]
  u16* Vt   = KVQd;                          // overlays (dead after G3)
  u16* KV   = p;  p += (size_t)4096 * 5120;  // Kc|V|Kr        [4096,5120]
  u16* Qb   = p;  p += (size_t)4096 * 3072;  // Qc|Qr          [4096,3072]
  u16* xc   = Qb;                            // overlays Q (dead after G1)

  convert_x<<<dim3(8192), 256, 0, stream>>>(x, xc, 4096 * 2048 / 4);
  convert_biases<<<dim3(48), 256, 0, stream>>>(kvdb, qdb, kub, vub, krb, qub, qrb, ob, bc);

  auto T = [&](const float* in, u16* out, int R, int C) {
    transpose_w<<<dim3(C / 32, R / 32), 256, 0, stream>>>(in, out, R, C);
  };
  T(kvdw, WT1, 2048, 512);
  T(qdw,  WT1 + (size_t)512 * 2048, 2048, 1536);
  T(kuw,  WT2, 512, 2048);
  T(vuw,  WT2 + (size_t)2048 * 512, 512, 2048);
  T(krw,  WT2 + (size_t)4096 * 512, 512, 1024);
  T(quw,  WT3, 1536, 2048);
  T(qrw,  WT3 + (size_t)2048 * 1536, 1536, 1024);
  T(ow,   WTo, 2048, 2048);

  auto G = [&](const u16* A, int lda, const u16* Bt, const u16* bias,
               void* Cout, int ldc, int wf32, int N, int K) {
    gemm_bt<<<dim3(N / 128, 4096 / 128), 256, 0, stream>>>(A, lda, Bt, bias, Cout, ldc, wf32, N, K);
  };
  G(xc, 2048, WT1, bc, KVQd, 2048, 0, 2048, 2048);                 // kv_c | q_c
  G(KVQd, 2048, WT2, bc + 2048, KV, LDKV, 0, 5120, 512);           // Kc | V | Kr
  G(KVQd + 512, 2048, WT3, bc + 7168, Qb, LDQ, 0, 3072, 1536);     // Qc | Qr

  rope_inplace<<<dim3((NB * SQ * NH * 32) / 256), 256, 0, stream>>>(KV, LDKV, 4096);
  rope_inplace<<<dim3((NB * SQ * NH * 32) / 256), 256, 0, stream>>>(Qb, LDQ, 2048);
  transpose_v<<<dim3(SQ / 32, HD / 32, NB * NH), 256, 0, stream>>>(KV, Vt);
  flash_attn<<<dim3(16, 32), 512, 0, stream>>>(Qb, KV, Vt, Ctx);

  G(Ctx, 2048, WTo, bc + 10240, d_out, 2048, 1, 2048, 2048);       // out proj (f32)
}

// Round 7
// 523.353 us; speedup vs baseline: 1.0243x; 1.0243x over previous
//
#include <hip/hip_runtime.h>

typedef unsigned short u16;
typedef short short8 __attribute__((ext_vector_type(8)));
typedef short short4v __attribute__((ext_vector_type(4)));
typedef float floatx4 __attribute__((ext_vector_type(4)));
typedef float floatx4v __attribute__((ext_vector_type(4)));

#define SQ 2048
#define NH 16
#define HD 128
#define RD 64
#define NB 2
#define LDKV 5120
#define LDQ 3072

// padded LDS strides (odd multiples of 8 u16 = 16 B)
#define LKC 136
#define LKR 72
#define LVT 72
#define LP  72

__device__ __forceinline__ float bf2f(u16 u) {
  union { unsigned u; float f; } v; v.u = ((unsigned)u) << 16; return v.f;
}
__device__ __forceinline__ u16 f2bf(float f) {
  union { float f; unsigned u; } v; v.f = f;
  return (u16)((v.u + 0x7FFFu + ((v.u >> 16) & 1u)) >> 16);
}
__device__ __forceinline__ void gll16(const u16* g, u16* l) {
  __builtin_amdgcn_global_load_lds((const __attribute__((address_space(1))) void*)g,
                                   (__attribute__((address_space(3))) void*)l, 16, 0, 0);
}

// ---- x (f32) -> bf16, vectorized ----
__global__ __launch_bounds__(256) void convert_x(const float* __restrict__ src,
                                                 u16* __restrict__ dst, int n4) {
  const int i = blockIdx.x * 256 + threadIdx.x;
  if (i >= n4) return;
  const floatx4v v = *(const floatx4v*)(src + 4 * (size_t)i);
  short4v o;
  o.x = (short)f2bf(v.x); o.y = (short)f2bf(v.y);
  o.z = (short)f2bf(v.z); o.w = (short)f2bf(v.w);
  *(short4v*)(dst + 4 * (size_t)i) = o;
}

// ---- all 8 biases (f32) -> concatenated bf16 slots ----
__global__ __launch_bounds__(256) void convert_biases(
    const float* b0, const float* b1, const float* b2, const float* b3,
    const float* b4, const float* b5, const float* b6, const float* b7,
    u16* __restrict__ bc) {
  const int i = blockIdx.x * 256 + threadIdx.x;
  if (i >= 12288) return;
  float v;
  if      (i < 512)   v = b0[i];          // kvdb
  else if (i < 2048)  v = b1[i - 512];    // qdb
  else if (i < 4096)  v = b2[i - 2048];   // kub
  else if (i < 6144)  v = b3[i - 4096];   // vub
  else if (i < 7168)  v = b4[i - 6144];   // krb
  else if (i < 9216)  v = b5[i - 7168];   // qub
  else if (i < 10240) v = b6[i - 9216];   // qrb
  else                v = b7[i - 10240];  // ob
  bc[i] = f2bf(v);
}

// ---- weight transpose: in[R][C] f32 -> out[C][R] bf16 ----
__global__ __launch_bounds__(256) void transpose_w(const float* __restrict__ in,
                                                   u16* __restrict__ out,
                                                   int R, int C) {
  __shared__ u16 tile[32][33];
  const int c0 = blockIdx.x * 32, r0 = blockIdx.y * 32;
  const int x = threadIdx.x & 31, y = threadIdx.x >> 5;
#pragma unroll
  for (int i = 0; i < 32; i += 8)
    tile[y + i][x] = f2bf(in[(size_t)(r0 + y + i) * C + c0 + x]);
  __syncthreads();
#pragma unroll
  for (int i = 0; i < 32; i += 8)
    out[(size_t)(c0 + y + i) * R + r0 + x] = tile[x][y + i];
}

// ---- V (cols 2048..4095 of KV [4096,5120]) -> Vt [B,H,HD,S] ----
__global__ __launch_bounds__(256) void transpose_v(const u16* __restrict__ KV,
                                                   u16* __restrict__ Vt) {
  __shared__ u16 tile[32][33];
  const int bh = blockIdx.z, b = bh >> 4, hh = bh & 15;
  const u16* pin = KV + (size_t)b * SQ * LDKV + 2048 + (size_t)hh * HD;
  u16* pout = Vt + (size_t)bh * HD * SQ;
  const int s0 = blockIdx.x * 32, d0 = blockIdx.y * 32;
  const int x = threadIdx.x & 31, y = threadIdx.x >> 5;
#pragma unroll
  for (int i = 0; i < 32; i += 8)
    tile[y + i][x] = pin[(size_t)(s0 + y + i) * LDKV + d0 + x];
  __syncthreads();
#pragma unroll
  for (int i = 0; i < 32; i += 8)
    pout[(size_t)(d0 + y + i) * SQ + s0 + x] = tile[x][y + i];
}

// ---- RoPE in place on a [4096 x (16*64)] submatrix at col `coloff`, ld `ld` ----
__global__ __launch_bounds__(256) void rope_inplace(u16* __restrict__ buf,
                                                    int ld, int coloff) {
  const int i = blockIdx.x * 256 + threadIdx.x;
  if (i >= NB * SQ * NH * 32) return;
  const int j = i & 31;
  const int hh = (i >> 5) & 15;
  const int row = i >> 9;
  const int s = row & (SQ - 1);
  u16* p = buf + (size_t)row * ld + coloff + hh * RD + 2 * j;
  const float x1 = bf2f(p[0]), x2 = bf2f(p[1]);
  const float inv = exp2f(-(float)j * 0.41524101186092031f);  // 10000^(-j/32)
  const float ang = (float)s * inv;
  float sn, cs;
  sincosf(ang, &sn, &cs);
  p[0] = f2bf(x1 * cs - x2 * sn);
  p[1] = f2bf(x1 * sn + x2 * cs);
}

// ---- C[M=4096,N] = A[.,K](lda) * Bt[N,K]^T + bias; out bf16(ldc) or f32 ----
// r7: 8 waves / 512 threads per 128^2 tile (was 4 waves). r6 post-mortem: the
// GEMMs sat at ~390 TF because grids of 512 blocks x 4 waves = 8 waves/CU
// (2/SIMD) — no TLP to hide the stage latency; source-level dbuf can't fix it
// (the barrier still drains vmcnt(0), m99/m100). Doubling waves/block doubles
// resident waves: 16/CU (4/SIMD), the same lever that paid -54us on flash (r3).
// Wave layout 2Mx4N: per-wave 64x32 out, acc[4][2] (~80 VGPR, 4-waves/SIMD
// bracket holds). Each [128][32] buffer fills with ONE gll16 by 512 threads
// (dest offset = t*16B: linear, wave-uniform base + lane*16 honored). BK=64
// split K-half buffers kept from r4/r5 (proven); dbuf + XCD swizzle dropped
// (r6: neutral; swizzle costs ~2% when L3-fit). MFMA accumulation order per
// output unchanged -> numerics identical.
__global__ __launch_bounds__(512, 4) void gemm_bt(const u16* __restrict__ A, int lda,
                                                  const u16* __restrict__ Bt,
                                                  const u16* __restrict__ bias,
                                                  void* __restrict__ Cout, int ldc,
                                                  int wf32, int N, int K) {
  __shared__ __align__(16) u16 lAk0[128 * 32];
  __shared__ __align__(16) u16 lAk1[128 * 32];
  __shared__ __align__(16) u16 lBk0[128 * 32];
  __shared__ __align__(16) u16 lBk1[128 * 32];
  const int t = threadIdx.x;
  const int lane = t & 63, w = t >> 6;      // 8 waves
  const int wm = w & 1, wn = w >> 1;        // 2 M-halves x 4 N-quarters
  const int m0 = blockIdx.y * 128, n0 = blockIdx.x * 128;
  const int srow = t >> 2, scol = (t & 3) * 8;  // 512 thr cover [128][32] once
  const u16* gA = A + (size_t)(m0 + srow) * lda + scol;
  const u16* gB = Bt + (size_t)(n0 + srow) * K + scol;
  u16* const ldA0 = lAk0 + (16 * w) * 32;   // wave-uniform gll16 dests
  u16* const ldA1 = lAk1 + (16 * w) * 32;
  u16* const ldB0 = lBk0 + (16 * w) * 32;
  u16* const ldB1 = lBk1 + (16 * w) * 32;
  const int lane_m = lane & 15, lane_k = (lane >> 4) * 8;
  floatx4 acc[4][2] = {};
  for (int k0 = 0; k0 < K; k0 += 64) {
    gll16(gA + k0, ldA0);
    gll16(gA + k0 + 32, ldA1);
    gll16(gB + k0, ldB0);
    gll16(gB + k0 + 32, ldB1);
    __syncthreads();
    {
      short8 af[4], bf[2];
#pragma unroll
      for (int i = 0; i < 4; i++)
        af[i] = *(const short8*)(lAk0 + (wm * 64 + i * 16 + lane_m) * 32 + lane_k);
#pragma unroll
      for (int i = 0; i < 2; i++)
        bf[i] = *(const short8*)(lBk0 + (wn * 32 + i * 16 + lane_m) * 32 + lane_k);
#pragma unroll
      for (int mi = 0; mi < 4; mi++)
#pragma unroll
        for (int ni = 0; ni < 2; ni++)
          acc[mi][ni] = __builtin_amdgcn_mfma_f32_16x16x32_bf16(af[mi], bf[ni], acc[mi][ni], 0, 0, 0);
    }
    {
      short8 af[4], bf[2];
#pragma unroll
      for (int i = 0; i < 4; i++)
        af[i] = *(const short8*)(lAk1 + (wm * 64 + i * 16 + lane_m) * 32 + lane_k);
#pragma unroll
      for (int i = 0; i < 2; i++)
        bf[i] = *(const short8*)(lBk1 + (wn * 32 + i * 16 + lane_m) * 32 + lane_k);
#pragma unroll
      for (int mi = 0; mi < 4; mi++)
#pragma unroll
        for (int ni = 0; ni < 2; ni++)
          acc[mi][ni] = __builtin_amdgcn_mfma_f32_16x16x32_bf16(af[mi], bf[ni], acc[mi][ni], 0, 0, 0);
    }
    __syncthreads();
  }
  const int quad = lane >> 4;
#pragma unroll
  for (int ni = 0; ni < 2; ni++) {
    const int col = n0 + wn * 32 + ni * 16 + lane_m;
    const float bv = bf2f(bias[col]);
#pragma unroll
    for (int mi = 0; mi < 4; mi++) {
      const int row = m0 + wm * 64 + mi * 16 + quad * 4;
      if (wf32) {
        float* pc = (float*)Cout + (size_t)row * ldc + col;
#pragma unroll
        for (int r = 0; r < 4; r++)
          pc[(size_t)r * ldc] = acc[mi][ni][r] + bv;
      } else {
        u16* pc = (u16*)Cout + (size_t)row * ldc + col;
#pragma unroll
        for (int r = 0; r < 4; r++)
          pc[(size_t)r * ldc] = f2bf(acc[mi][ni][r] + bv);
      }
    }
  }
}

// ---- flash attention: grid (16, 32); 8 waves, 128 q-rows/block, 64-key tiles ----
// Verified r5/r6 structure (158 us): reg-staged 1-deep prefetch, setprio around
// MFMA clusters, T13 defer-max (VALUBusy -3, time-neutral, kept). Untouched
// this round for clean attribution of the GEMM re-tile.
__global__ __launch_bounds__(512, 4) void flash_attn(const u16* __restrict__ Q,
                                                     const u16* __restrict__ KV,
                                                     const u16* __restrict__ Vt,
                                                     u16* __restrict__ Ctx) {
  __shared__ __align__(16) u16 lKc[64 * LKC];
  __shared__ __align__(16) u16 lKr[64 * LKR];
  __shared__ __align__(16) u16 lVt[128 * LVT];
  __shared__ __align__(16) u16 lP[8 * 16 * LP];
  const int t = threadIdx.x, lane = t & 63, w = t >> 6;
  const int col = blockIdx.y;
  const int qtile = (col < 16) ? (15 - (int)blockIdx.x) : (int)blockIdx.x;
  const int h = col & (NH - 1);
  const int b = col >> 4;
  const int q0 = qtile * 128;
  const int nkt = 2 * qtile + 2;
  const int lane_m = lane & 15, quad = lane >> 4, lane_k = quad * 8;

  // Q fragments (A-operand), one 16-row stripe per wave
  const int qrow = q0 + 16 * w + lane_m;
  const u16* qcp = Q + (size_t)(b * SQ + qrow) * LDQ + h * HD;
  const u16* qrp = Q + (size_t)(b * SQ + qrow) * LDQ + 2048 + h * RD;
  short8 qfc[4], qfr[2];
#pragma unroll
  for (int ks = 0; ks < 4; ks++) qfc[ks] = *(const short8*)(qcp + ks * 32 + lane_k);
#pragma unroll
  for (int ks = 0; ks < 2; ks++) qfr[ks] = *(const short8*)(qrp + ks * 32 + lane_k);

  floatx4 O[8] = {};
  float mrow[4], lsum[4];
#pragma unroll
  for (int r = 0; r < 4; r++) { mrow[r] = -1e30f; lsum[r] = 0.f; }

  const u16* gKc = KV + (size_t)b * SQ * LDKV + h * HD;          // + key*LDKV + d
  const u16* gKr = KV + (size_t)b * SQ * LDKV + 4096 + h * RD;   // + key*LDKV + d
  const u16* gVt = Vt + (size_t)(b * NH + h) * HD * SQ;          // + d*SQ + key
  const float C2 = 0.10412825525540364f;  // (1/sqrt(192)) * log2(e)
  const float THR = 28.8f;                // defer-max threshold: exp2(THR*C2)=8

  // register staging (global -> reg prefetch -> LDS), 512 threads
  short8 rKc[2], rKr, rVt[2];
  auto load_tile = [&](int kb) {
#pragma unroll
    for (int i = 0; i < 2; i++) {
      const int c = t + i * 512, row = c >> 4, cc = (c & 15) * 8;
      rKc[i] = *(const short8*)(gKc + (size_t)(kb + row) * LDKV + cc);
    }
    {
      const int row = t >> 3, cc = (t & 7) * 8;
      rKr = *(const short8*)(gKr + (size_t)(kb + row) * LDKV + cc);
    }
#pragma unroll
    for (int i = 0; i < 2; i++) {
      const int c = t + i * 512, row = c >> 3, cc = (c & 7) * 8;
      rVt[i] = *(const short8*)(gVt + (size_t)row * SQ + kb + cc);
    }
  };

  const int wrow_lo = q0 + 16 * w;
  const int wrow_hi = wrow_lo + 15;

  load_tile(0);
  for (int kt = 0; kt < nkt; kt++) {
    const int kb = kt * 64;
    __syncthreads();  // previous tile's LDS reads complete
#pragma unroll
    for (int i = 0; i < 2; i++) {
      const int c = t + i * 512, row = c >> 4, cc = (c & 15) * 8;
      *(short8*)(lKc + row * LKC + cc) = rKc[i];
    }
    {
      const int row = t >> 3, cc = (t & 7) * 8;
      *(short8*)(lKr + row * LKR + cc) = rKr;
    }
#pragma unroll
    for (int i = 0; i < 2; i++) {
      const int c = t + i * 512, row = c >> 3, cc = (c & 7) * 8;
      *(short8*)(lVt + row * LVT + cc) = rVt[i];
    }
    __syncthreads();
    if (kt < nkt - 1) load_tile(kb + 64);  // prefetch overlaps compute below

    if (kb <= wrow_hi) {  // wave-level skip of fully-masked tiles (barriers stay uniform)
      float ss[4][4];
      __builtin_amdgcn_s_setprio(1);
#pragma unroll
      for (int n = 0; n < 4; n++) {
        floatx4 a = {0.f, 0.f, 0.f, 0.f};
#pragma unroll
        for (int ks = 0; ks < 4; ks++) {
          const short8 kf = *(const short8*)(lKc + (n * 16 + lane_m) * LKC + ks * 32 + lane_k);
          a = __builtin_amdgcn_mfma_f32_16x16x32_bf16(qfc[ks], kf, a, 0, 0, 0);
        }
#pragma unroll
        for (int ks = 0; ks < 2; ks++) {
          const short8 kf = *(const short8*)(lKr + (n * 16 + lane_m) * LKR + ks * 32 + lane_k);
          a = __builtin_amdgcn_mfma_f32_16x16x32_bf16(qfr[ks], kf, a, 0, 0, 0);
        }
#pragma unroll
        for (int r = 0; r < 4; r++) ss[n][r] = a[r];
      }
      __builtin_amdgcn_s_setprio(0);
      if (kb + 63 > wrow_lo) {  // causal mask (partial tiles)
#pragma unroll
        for (int n = 0; n < 4; n++) {
          const int kcol = kb + n * 16 + lane_m;
#pragma unroll
          for (int r = 0; r < 4; r++) {
            const int row = wrow_lo + quad * 4 + r;
            if (kcol > row) ss[n][r] = -1e30f;
          }
        }
      }
      // per-row tile max
      float mt[4];
#pragma unroll
      for (int r = 0; r < 4; r++) {
        float m = fmaxf(fmaxf(ss[0][r], ss[1][r]), fmaxf(ss[2][r], ss[3][r]));
#pragma unroll
        for (int d = 1; d < 16; d <<= 1) m = fmaxf(m, __shfl_xor(m, d));
        mt[r] = m;
      }
      // T13 defer-max: rescale only if some row grew past THR
      const bool grow = (mt[0] > mrow[0] + THR) || (mt[1] > mrow[1] + THR) ||
                        (mt[2] > mrow[2] + THR) || (mt[3] > mrow[3] + THR);
      if (__any(grow)) {
#pragma unroll
        for (int r = 0; r < 4; r++) {
          const float mn = fmaxf(mrow[r], mt[r]);
          const float alpha = exp2f((mrow[r] - mn) * C2);
          mrow[r] = mn;
          lsum[r] *= alpha;
#pragma unroll
          for (int vb = 0; vb < 8; vb++) O[vb][r] *= alpha;
        }
      }
      float pw[4][4];
#pragma unroll
      for (int r = 0; r < 4; r++) {
        float s = 0.f;
#pragma unroll
        for (int n = 0; n < 4; n++) {
          const float p = exp2f((ss[n][r] - mrow[r]) * C2);
          pw[n][r] = p;
          s += p;
        }
#pragma unroll
        for (int d = 1; d < 16; d <<= 1) s += __shfl_xor(s, d);
        lsum[r] += s;
      }
      // P: C-layout -> LDS (per-wave region) -> A-layout
#pragma unroll
      for (int n = 0; n < 4; n++)
#pragma unroll
        for (int r = 0; r < 4; r++)
          lP[(w * 16 + quad * 4 + r) * LP + n * 16 + lane_m] = f2bf(pw[n][r]);
      asm volatile("s_waitcnt lgkmcnt(0)" ::: "memory");
      __builtin_amdgcn_s_setprio(1);
#pragma unroll
      for (int ks = 0; ks < 2; ks++) {
        const short8 pf = *(const short8*)(lP + (w * 16 + lane_m) * LP + ks * 32 + lane_k);
#pragma unroll
        for (int vb = 0; vb < 8; vb++) {
          const short8 vf = *(const short8*)(lVt + (vb * 16 + lane_m) * LVT + ks * 32 + lane_k);
          O[vb] = __builtin_amdgcn_mfma_f32_16x16x32_bf16(pf, vf, O[vb], 0, 0, 0);
        }
      }
      __builtin_amdgcn_s_setprio(0);
    }
  }
  float inv[4];
#pragma unroll
  for (int r = 0; r < 4; r++) inv[r] = 1.f / lsum[r];
#pragma unroll
  for (int vb = 0; vb < 8; vb++) {
#pragma unroll
    for (int r = 0; r < 4; r++) {
      const int row = wrow_lo + quad * 4 + r;
      Ctx[(size_t)(b * SQ + row) * 2048 + h * HD + vb * 16 + lane_m] = f2bf(O[vb][r] * inv[r]);
    }
  }
}

extern "C" void kernel_launch(void* const* d_in, const int* in_sizes, int n_in,
                              void* d_out, int out_size, void* d_ws, size_t ws_size,
                              hipStream_t stream) {
  (void)in_sizes; (void)n_in; (void)out_size; (void)ws_size;
  const float* x    = (const float*)d_in[0];
  const float* kvdw = (const float*)d_in[2];
  const float* kvdb = (const float*)d_in[3];
  const float* kuw  = (const float*)d_in[4];
  const float* kub  = (const float*)d_in[5];
  const float* vuw  = (const float*)d_in[6];
  const float* vub  = (const float*)d_in[7];
  const float* krw  = (const float*)d_in[8];
  const float* krb  = (const float*)d_in[9];
  const float* qdw  = (const float*)d_in[10];
  const float* qdb  = (const float*)d_in[11];
  const float* quw  = (const float*)d_in[12];
  const float* qub  = (const float*)d_in[13];
  const float* qrw  = (const float*)d_in[14];
  const float* qrb  = (const float*)d_in[15];
  const float* ow   = (const float*)d_in[16];
  const float* ob   = (const float*)d_in[17];

  // workspace layout (u16 units), ~115 MB, lifetime-aliased
  u16* p = (u16*)d_ws;
  u16* bc   = p;  p += 16384;
  u16* WT1  = p;  p += (size_t)2048 * 2048;  // kvd^T | qd^T   [2048,2048]
  u16* WT2  = p;  p += (size_t)5120 * 512;   // ku^T|vu^T|kr^T [5120,512]
  u16* WT3  = p;  p += (size_t)3072 * 1536;  // qu^T|qr^T      [3072,1536]
  u16* Ctx  = WT1;                           // overlays WT1..WT3 (dead by flash)
  u16* WTo  = p;  p += (size_t)2048 * 2048;  // o^T            [2048,2048]
  u16* KVQd = p;  p += (size_t)4096 * 2048;  // kv_c|q_c       [4096,2048]
  u16* Vt   = KVQd;                          // overlays (dead after G3)
  u16* KV   = p;  p += (size_t)4096 * 5120;  // Kc|V|Kr        [4096,5120]
  u16* Qb   = p;  p += (size_t)4096 * 3072;  // Qc|Qr          [4096,3072]
  u16* xc   = Qb;                            // overlays Q (dead after G1)

  convert_x<<<dim3(8192), 256, 0, stream>>>(x, xc, 4096 * 2048 / 4);
  convert_biases<<<dim3(48), 256, 0, stream>>>(kvdb, qdb, kub, vub, krb, qub, qrb, ob, bc);

  auto T = [&](const float* in, u16* out, int R, int C) {
    transpose_w<<<dim3(C / 32, R / 32), 256, 0, stream>>>(in, out, R, C);
  };
  T(kvdw, WT1, 2048, 512);
  T(qdw,  WT1 + (size_t)512 * 2048, 2048, 1536);
  T(kuw,  WT2, 512, 2048);
  T(vuw,  WT2 + (size_t)2048 * 512, 512, 2048);
  T(krw,  WT2 + (size_t)4096 * 512, 512, 1024);
  T(quw,  WT3, 1536, 2048);
  T(qrw,  WT3 + (size_t)2048 * 1536, 1536, 1024);
  T(ow,   WTo, 2048, 2048);

  auto G = [&](const u16* A, int lda, const u16* Bt, const u16* bias,
               void* Cout, int ldc, int wf32, int N, int K) {
    gemm_bt<<<dim3(N / 128, 4096 / 128), 512, 0, stream>>>(A, lda, Bt, bias, Cout, ldc, wf32, N, K);
  };
  G(xc, 2048, WT1, bc, KVQd, 2048, 0, 2048, 2048);                 // kv_c | q_c
  G(KVQd, 2048, WT2, bc + 2048, KV, LDKV, 0, 5120, 512);           // Kc | V | Kr
  G(KVQd + 512, 2048, WT3, bc + 7168, Qb, LDQ, 0, 3072, 1536);     // Qc | Qr

  rope_inplace<<<dim3((NB * SQ * NH * 32) / 256), 256, 0, stream>>>(KV, LDKV, 4096);
  rope_inplace<<<dim3((NB * SQ * NH * 32) / 256), 256, 0, stream>>>(Qb, LDQ, 2048);
  transpose_v<<<dim3(SQ / 32, HD / 32, NB * NH), 256, 0, stream>>>(KV, Vt);
  flash_attn<<<dim3(16, 32), 512, 0, stream>>>(Qb, KV, Vt, Ctx);

  G(Ctx, 2048, WTo, bc + 10240, d_out, 2048, 1, 2048, 2048);       // out proj (f32)
}